// Round 13
// baseline (669.347 us; speedup 1.0000x reference)
//
#include <hip/hip_runtime.h>
#include <math.h>

typedef unsigned short u16;
typedef __attribute__((ext_vector_type(8))) unsigned short ushort8;
typedef __attribute__((ext_vector_type(4))) unsigned short u16x4;
typedef __attribute__((ext_vector_type(8))) short short8;
typedef __attribute__((ext_vector_type(4))) float f32x4;

__device__ __forceinline__ float b2f(u16 v) {
    unsigned u = ((unsigned)v) << 16; float f; __builtin_memcpy(&f, &u, 4); return f;
}
__device__ __forceinline__ u16 f2b(float f) {
    unsigned u; __builtin_memcpy(&u, &f, 4);
    u = (u + 0x7fffu + ((u >> 16) & 1u)) >> 16;   // RNE
    return (u16)u;
}
// flag-branched raw-input load (flag: 1 = fp32 inputs, 0 = bf16 inputs)
__device__ __forceinline__ float ldin(const void* p, int i, int flag) {
    return flag ? ((const float*)p)[i] : b2f(((const u16*)p)[i]);
}
__device__ __forceinline__ void split2(float x, u16& h, u16& l) {
    h = f2b(x);
    l = f2b(x - b2f(h));
}
__device__ __forceinline__ ushort8 zero8() {
    ushort8 z;
#pragma unroll
    for (int i = 0; i < 8; ++i) z[i] = 0;
    return z;
}
// Non-draining tile barrier: flush own LDS writes (lgkmcnt only), raw
// s_barrier. Prefetch global loads (vmcnt) stay IN FLIGHT across it.
__device__ __forceinline__ void tile_barrier() {
    asm volatile("s_waitcnt lgkmcnt(0)" ::: "memory");
    __builtin_amdgcn_s_barrier();
    asm volatile("" ::: "memory");
}

// ---------------------------------------------------------------------------
// dtype detector: fp32 N(0,1) words have exponent field in [77,157];
// bf16 pairs viewed as fp32 essentially never do. flag=1 -> fp32.
// ---------------------------------------------------------------------------
__global__ void detect_kernel(const unsigned* __restrict__ xw, int* __restrict__ flag) {
    __shared__ int red[4];
    int tid = threadIdx.x, lane = tid & 63, wid = tid >> 6;
    int cnt = 0;
    for (int i = 0; i < 16; ++i) {
        unsigned w = xw[tid * 16 + i];
        unsigned e = (w >> 23) & 0xFF;
        if (e >= 77u && e <= 157u) ++cnt;
    }
    for (int o = 32; o; o >>= 1) cnt += __shfl_down(cnt, o, 64);
    if (lane == 0) red[wid] = cnt;
    __syncthreads();
    if (tid == 0) flag[0] = (red[0] + red[1] + red[2] + red[3] >= 2048) ? 1 : 0;
}

// ---------------------------------------------------------------------------
// Parallel spectral norm. t layout: [0]=t1(2304) [2304]=t2(2304) [4608]=ts(256)
// ---------------------------------------------------------------------------
__global__ void sig_init_kernel(float* __restrict__ t, float* __restrict__ ns) {
    int i = blockIdx.x * 256 + threadIdx.x;
    if (i < 4864) t[i] = 0.f;
    if (i < 3) ns[i] = 0.f;
}

// t = W^T u, grid-parallel over (weight, j-chunk of 256, i-chunk of 64)
__global__ void sig_t_kernel(const void* __restrict__ w1, const void* __restrict__ u1,
                             const void* __restrict__ w2, const void* __restrict__ u2,
                             const void* __restrict__ wsb, const void* __restrict__ us,
                             const int* __restrict__ flagp, float* __restrict__ t) {
    __shared__ float ush[64];
    int blk = blockIdx.x;
    int flag = flagp[0];
    const void* W; const void* U; int m, toff, jc, ic;
    if (blk < 36)       { W = w1;  U = u1; m = 2304; toff = 0;    jc = blk % 9; ic = blk / 9; }
    else if (blk < 108) { int r = blk - 36;  W = w2;  U = u2; m = 2304; toff = 2304; jc = r % 9; ic = r / 9; }
    else                { int r = blk - 108; W = wsb; U = us; m = 256;  toff = 4608; jc = 0;     ic = r; }
    int tid = threadIdx.x;
    if (tid < 64) ush[tid] = ldin(U, ic * 64 + tid, flag);
    __syncthreads();
    int j = jc * 256 + tid;
    float acc = 0.f;
    int base = ic * 64 * m + j;
    for (int ii = 0; ii < 64; ++ii) acc += ldin(W, base + ii * m, flag) * ush[ii];
    atomicAdd(&t[toff + j], acc);
}

__global__ void sig_norm_kernel(float* __restrict__ t, float* __restrict__ ntinv) {
    __shared__ float red[4];
    int b = blockIdx.x;
    int m = (b == 2) ? 256 : 2304;
    int toff = b * 2304;
    int tid = threadIdx.x, lane = tid & 63, wid = tid >> 6;
    float s = 0.f;
    for (int j = tid; j < m; j += 256) { float v = t[toff + j]; s += v * v; }
    for (int o = 32; o; o >>= 1) s += __shfl_down(s, o, 64);
    if (lane == 0) red[wid] = s;
    __syncthreads();
    if (tid == 0) ntinv[b] = 1.f / (sqrtf(red[0] + red[1] + red[2] + red[3]) + 1e-12f);
}

// s_i = (W t)_i * ntinv ; ns_b += s_i^2. One wave per row.
__global__ void sig_s_kernel(const void* __restrict__ w1, const void* __restrict__ w2,
                             const void* __restrict__ wsb, const int* __restrict__ flagp,
                             const float* __restrict__ t, const float* __restrict__ ntinv,
                             float* __restrict__ ns) {
    int flag = flagp[0];
    int wg = blockIdx.x * 4 + (threadIdx.x >> 6);   // 0..1279
    int lane = threadIdx.x & 63;
    const void* W; int m, toff, i, b;
    if (wg < 256)      { W = w1;  m = 2304; toff = 0;    i = wg;       b = 0; }
    else if (wg < 768) { W = w2;  m = 2304; toff = 2304; i = wg - 256; b = 1; }
    else               { W = wsb; m = 256;  toff = 4608; i = wg - 768; b = 2; }
    float acc = 0.f;
    int base = i * m;
    for (int j = lane; j < m; j += 64) acc += ldin(W, base + j, flag) * t[toff + j];
    for (int o = 32; o; o >>= 1) acc += __shfl_down(acc, o, 64);
    if (lane == 0) { float s = acc * ntinv[b]; atomicAdd(&ns[b], s * s); }
}

__global__ void sig_fin_kernel(const float* __restrict__ ns, float* __restrict__ inv_sigma) {
    int b = threadIdx.x;
    if (b < 3) { float s2 = ns[b]; float s = sqrtf(s2); inv_sigma[b] = (s + 1e-12f) / s2; }
}

// ---------------------------------------------------------------------------
// Weight prep: scale by 1/sigma, transpose to [kyx][co][ci], split hi/lo.
// Also canonicalizes biases to fp32.
// ---------------------------------------------------------------------------
__global__ void wprep_kernel(const void* __restrict__ w1b, const void* __restrict__ w2b,
                             const void* __restrict__ wsb,
                             const void* __restrict__ b1,  const void* __restrict__ b2,
                             const float* __restrict__ inv_sigma, const int* __restrict__ flagp,
                             u16* __restrict__ w1h, u16* __restrict__ w1l,
                             u16* __restrict__ w2h, u16* __restrict__ w2l,
                             u16* __restrict__ wsh, u16* __restrict__ wsl,
                             float* __restrict__ b1f, float* __restrict__ b2f_) {
    int idx = blockIdx.x * 256 + threadIdx.x;
    int flag = flagp[0];
    float s0 = inv_sigma[0], s1 = inv_sigma[1], s2 = inv_sigma[2];
    if (idx < 589824) {                       // 9*256*256
        int kyx = idx / 65536; int rem = idx - kyx * 65536;
        int co = rem >> 8, ci = rem & 255;
        float w = ldin(w1b, ((co << 8) + ci) * 9 + kyx, flag) * s0;
        split2(w, w1h[idx], w1l[idx]);
    } else if (idx < 589824 + 1179648) {      // 9*512*256
        int i2 = idx - 589824;
        int kyx = i2 / 131072; int rem = i2 - kyx * 131072;
        int co = rem >> 8, ci = rem & 255;
        float w = ldin(w2b, ((co << 8) + ci) * 9 + kyx, flag) * s1;
        split2(w, w2h[i2], w2l[i2]);
    } else if (idx < 1900544) {               // 512*256
        int i3 = idx - 1769472;
        float w = ldin(wsb, i3, flag) * s2;
        split2(w, wsh[i3], wsl[i3]);
    } else if (idx < 1900544 + 256) {
        b1f[idx - 1900544] = ldin(b1, idx - 1900544, flag);
    } else if (idx < 1900544 + 768) {
        b2f_[idx - 1900800] = ldin(b2, idx - 1900800, flag);
    }
}

// ---------------------------------------------------------------------------
// x NCHW -> xt bf16-hi/lo NHWC planes for one 8-image chunk.
// Vectorized input path: branch once on flag, float4/ushort8 loads.
// ---------------------------------------------------------------------------
__global__ void transpose_kernel(const void* __restrict__ x, u16* __restrict__ xh,
                                 u16* __restrict__ xl,
                                 const int* __restrict__ flagp, int n0) {
    __shared__ float tile[32][65];
    int flag = flagp[0];
    int ny  = blockIdx.x;                    // nl*64 + y
    int ci0 = blockIdx.y * 32;
    int nl = ny >> 6, y = ny & 63;
    int t = threadIdx.x;
    int ci_l = t >> 3, x8 = (t & 7) * 8;
    int base = ((n0 + nl) * 256 + ci0 + ci_l) * 4096 + y * 64 + x8;
    if (flag) {
        const float* xf = (const float*)x;
        float4 v0 = *(const float4*)&xf[base];
        float4 v1 = *(const float4*)&xf[base + 4];
        tile[ci_l][x8 + 0] = v0.x; tile[ci_l][x8 + 1] = v0.y;
        tile[ci_l][x8 + 2] = v0.z; tile[ci_l][x8 + 3] = v0.w;
        tile[ci_l][x8 + 4] = v1.x; tile[ci_l][x8 + 5] = v1.y;
        tile[ci_l][x8 + 6] = v1.z; tile[ci_l][x8 + 7] = v1.w;
    } else {
        const u16* xb = (const u16*)x;
        ushort8 v = *(const ushort8*)&xb[base];
#pragma unroll
        for (int k = 0; k < 8; ++k) tile[ci_l][x8 + k] = b2f(v[k]);
    }
    __syncthreads();
    int x_l = t >> 2, oc = (t & 3) * 8;
    size_t o = ((size_t)ny * 64 + x_l) * 256 + ci0 + oc;
    ushort8 h, l;
#pragma unroll
    for (int k = 0; k < 8; ++k) {
        u16 hh, ll; split2(tile[oc + k][x_l], hh, ll);
        h[k] = hh; l[k] = ll;
    }
    *(ushort8*)&xh[o] = h;
    *(ushort8*)&xl[o] = l;
}

__device__ __constant__ float BW[4] = {0.125f, 0.375f, 0.375f, 0.125f};

// ---------------------------------------------------------------------------
// blur of act1 (bf16 hi/lo NHWC 64x64, 8 images) pad(2,2) -> blur1 hi/lo.
// 8 channels/thread, 16B ushort8 loads.
// ---------------------------------------------------------------------------
__global__ void blur1_kernel(const u16* __restrict__ a1h, const u16* __restrict__ a1l,
                             u16* __restrict__ bh, u16* __restrict__ bl) {
    int idx = blockIdx.x * 256 + threadIdx.x;     // 8*65*65*32
    int ch = (idx & 31) * 8;
    int rem = idx >> 5;
    int xq = rem % 65; rem /= 65;
    int yq = rem % 65;
    int n  = rem / 65;
    float acc[8];
#pragma unroll
    for (int k = 0; k < 8; ++k) acc[k] = 0.f;
#pragma unroll
    for (int i = 0; i < 4; ++i) {
        int yy = yq + i - 2;
        if ((unsigned)yy >= 64u) continue;
#pragma unroll
        for (int j = 0; j < 4; ++j) {
            int xx = xq + j - 2;
            if ((unsigned)xx >= 64u) continue;
            float w = BW[i] * BW[j];
            size_t g = ((size_t)((n * 64 + yy) * 64 + xx) << 8) + ch;
            ushort8 vh = *(const ushort8*)&a1h[g];
            ushort8 vl = *(const ushort8*)&a1l[g];
#pragma unroll
            for (int k = 0; k < 8; ++k) acc[k] += w * (b2f(vh[k]) + b2f(vl[k]));
        }
    }
    ushort8 h, l;
#pragma unroll
    for (int k = 0; k < 8; ++k) {
        u16 hh, ll; split2(acc[k], hh, ll);
        h[k] = hh; l[k] = ll;
    }
    size_t o = ((size_t)((n * 65 + yq) * 65 + xq) << 8) + ch;
    *(ushort8*)&bh[o] = h;
    *(ushort8*)&bl[o] = l;
}

// ---------------------------------------------------------------------------
// skip blur of xt (hi/lo planes) pad(1,1) at even pos -> skipin hi/lo planes.
// 8 channels/thread, 16B loads.
// ---------------------------------------------------------------------------
__global__ void blursample_kernel(const u16* __restrict__ xh, const u16* __restrict__ xl,
                                  u16* __restrict__ sh, u16* __restrict__ sl) {
    int idx = blockIdx.x * 256 + threadIdx.x;     // 8*32*32*32
    int ch = (idx & 31) * 8;
    int rem = idx >> 5;
    int xo = rem & 31;
    int yo = (rem >> 5) & 31;
    int n  = rem >> 10;
    float acc[8];
#pragma unroll
    for (int k = 0; k < 8; ++k) acc[k] = 0.f;
#pragma unroll
    for (int i = 0; i < 4; ++i) {
        int yy = 2 * yo + i - 1;
        if ((unsigned)yy >= 64u) continue;
#pragma unroll
        for (int j = 0; j < 4; ++j) {
            int xx = 2 * xo + j - 1;
            if ((unsigned)xx >= 64u) continue;
            float w = BW[i] * BW[j];
            size_t g = ((size_t)((n * 64 + yy) * 64 + xx) << 8) + ch;
            ushort8 vh = *(const ushort8*)&xh[g];
            ushort8 vl = *(const ushort8*)&xl[g];
#pragma unroll
            for (int k = 0; k < 8; ++k) acc[k] += w * (b2f(vh[k]) + b2f(vl[k]));
        }
    }
    ushort8 h, l;
#pragma unroll
    for (int k = 0; k < 8; ++k) {
        u16 hh, ll; split2(acc[k], hh, ll);
        h[k] = hh; l[k] = ll;
    }
    size_t o = ((size_t)((n * 32 + yo) * 32 + xo) << 8) + ch;
    *(ushort8*)&sh[o] = h;
    *(ushort8*)&sl[o] = l;
}

// ---------------------------------------------------------------------------
// conv1: tile 128x128, BK=32, LDS dbuf, one non-draining barrier/iter,
// pure-reg MFMA burst + setprio (round-11 proven). NEW: nested p x unrolled
// kc loops so all p-level address math hoists; kc*64B offsets are constants.
// Same addresses / same sync schedule as the flattened version.
// ---------------------------------------------------------------------------
#define LDK 40
#define C1_HALF (128 * LDK)

#define C1_LOADP(P_, KC_, RAH0, RAH1, RAL0, RAL1, RBH0, RBH1, RBL0, RBL1) {    \
    const u16* wh_ = w1h + (size_t)(P_) * 65536;                               \
    const u16* wl_ = w1l + (size_t)(P_) * 65536;                               \
    size_t gs_ = (size_t)(co_base + ra) * 256 + (KC_) * 32 + ka;               \
    RAH0 = *(const ushort8*)&wh_[gs_];                                         \
    RAH1 = *(const ushort8*)&wh_[gs_ + 8];                                     \
    if (DOLO) { RAL0 = *(const ushort8*)&wl_[gs_];                             \
                RAL1 = *(const ushort8*)&wl_[gs_ + 8]; }                       \
    int dy_ = (P_) / 3 - 1, dx_ = (P_) % 3 - 1;                                \
    int yy_ = y0 + (ra >> 6) + dy_, xx_ = (ra & 63) + dx_;                     \
    if ((unsigned)yy_ < 64u && (unsigned)xx_ < 64u) {                          \
        size_t g_ = ((size_t)((n * 64 + yy_) * 64 + xx_) << 8) + (KC_) * 32 + ka;\
        RBH0 = *(const ushort8*)&xh[g_];                                       \
        RBH1 = *(const ushort8*)&xh[g_ + 8];                                   \
        if (DOLO) { RBL0 = *(const ushort8*)&xl[g_];                           \
                    RBL1 = *(const ushort8*)&xl[g_ + 8]; }                     \
    } else {                                                                   \
        RBH0 = zero8(); RBH1 = zero8();                                        \
        if (DOLO) { RBL0 = zero8(); RBL1 = zero8(); }                          \
    }                                                                          \
}

#define C1_WRITE(OFF) {                                                        \
    *(ushort8*)&Ah[(OFF) + ra * LDK + ka]     = nAh0;                          \
    *(ushort8*)&Ah[(OFF) + ra * LDK + ka + 8] = nAh1;                          \
    if (DOLO) {                                                                \
        *(ushort8*)&Al[(OFF) + ra * LDK + ka]     = nAl0;                      \
        *(ushort8*)&Al[(OFF) + ra * LDK + ka + 8] = nAl1;                      \
    }                                                                          \
    *(ushort8*)&Bh[(OFF) + ra * LDK + ka]     = nBh0;                          \
    *(ushort8*)&Bh[(OFF) + ra * LDK + ka + 8] = nBh1;                          \
    if (DOLO) {                                                                \
        *(ushort8*)&Bl[(OFF) + ra * LDK + ka]     = nBl0;                      \
        *(ushort8*)&Bl[(OFF) + ra * LDK + ka + 8] = nBl1;                      \
    }                                                                          \
}

template <bool DOLO>
__device__ __forceinline__ void conv1_body(
        const u16* __restrict__ xh, const u16* __restrict__ xl,
        const u16* __restrict__ w1h, const u16* __restrict__ w1l,
        const float* __restrict__ b1f, u16* __restrict__ a1h, u16* __restrict__ a1l,
        u16* Ah, u16* Al, u16* Bh, u16* Bl) {
    int tid = threadIdx.x, lane = tid & 63, wid = tid >> 6;
    int col = lane & 15, quad = lane >> 4;
    int wco = (wid >> 1) * 64, wsp = (wid & 1) * 64;
    int bidx = blockIdx.x;                         // 256 sp blocks
    int sp_blk = (bidx & 7) * 32 + (bidx >> 3);    // XCD swizzle: image-per-XCD
    int sp_base = sp_blk * 128;                    // over 8*4096 (2 rows/tile)
    int co_base = blockIdx.y * 128;
    int n  = sp_base >> 12;
    int y0 = (sp_base & 4095) >> 6;
    int ra = tid >> 1, ka = (tid & 1) * 16;        // A & B staging: 128 rows x 2 slots

    f32x4 acc[4][4];
#pragma unroll
    for (int i = 0; i < 4; ++i)
#pragma unroll
        for (int j = 0; j < 4; ++j) acc[i][j] = (f32x4){0.f, 0.f, 0.f, 0.f};

    ushort8 nAh0, nAh1, nAl0, nAl1, nBh0, nBh1, nBl0, nBl1;
    // prologue: stage (0,0) into buf0, prefetch (0,1)
    C1_LOADP(0, 0, nAh0, nAh1, nAl0, nAl1, nBh0, nBh1, nBl0, nBl1);
    C1_WRITE(0);
    C1_LOADP(0, 1, nAh0, nAh1, nAl0, nAl1, nBh0, nBh1, nBl0, nBl1);
    tile_barrier();

    for (int p = 0; p < 9; ++p) {
#pragma unroll
        for (int kc = 0; kc < 8; ++kc) {
            const int cur = (kc & 1) ? C1_HALF : 0;   // it parity == kc parity
            const int nxt = (kc & 1) ? 0 : C1_HALF;
            // read ALL fragments from current buffer (pure-reg MFMA burst after)
            short8 ah[4], al[4], bhf[4], blf[4];
#pragma unroll
            for (int tm = 0; tm < 4; ++tm) {
                ah[tm] = *(const short8*)&Ah[cur + (wco + tm * 16 + col) * LDK + quad * 8];
                if (DOLO) al[tm] = *(const short8*)&Al[cur + (wco + tm * 16 + col) * LDK + quad * 8];
            }
#pragma unroll
            for (int tn = 0; tn < 4; ++tn) {
                bhf[tn] = *(const short8*)&Bh[cur + (wsp + tn * 16 + col) * LDK + quad * 8];
                if (DOLO) blf[tn] = *(const short8*)&Bl[cur + (wsp + tn * 16 + col) * LDK + quad * 8];
            }
            // write NEXT tile (regs hold (p,kc)+1's data, loads issued last iter)
            C1_WRITE(nxt);
            // prefetch (p,kc)+2 — compile-time boundary split: p-math hoists
            if (kc < 6) {
                C1_LOADP(p, kc + 2, nAh0, nAh1, nAl0, nAl1, nBh0, nBh1, nBl0, nBl1);
            } else {
                int pp = (p < 8) ? p + 1 : 8;
                int kk = (p < 8) ? kc - 6 : 7;       // tail clamps to (8,7)
                C1_LOADP(pp, kk, nAh0, nAh1, nAl0, nAl1, nBh0, nBh1, nBl0, nBl1);
            }
            __builtin_amdgcn_s_setprio(1);
#pragma unroll
            for (int tn = 0; tn < 4; ++tn)
#pragma unroll
                for (int tm = 0; tm < 4; ++tm) {
                    acc[tm][tn] = __builtin_amdgcn_mfma_f32_16x16x32_bf16(ah[tm], bhf[tn], acc[tm][tn], 0, 0, 0);
                    if (DOLO) {
                        acc[tm][tn] = __builtin_amdgcn_mfma_f32_16x16x32_bf16(ah[tm], blf[tn], acc[tm][tn], 0, 0, 0);
                        acc[tm][tn] = __builtin_amdgcn_mfma_f32_16x16x32_bf16(al[tm], bhf[tn], acc[tm][tn], 0, 0, 0);
                    }
                }
            __builtin_amdgcn_s_setprio(0);
            tile_barrier();                        // one barrier/iter; loads fly
        }
    }
#pragma unroll
    for (int tm = 0; tm < 4; ++tm) {
        int cog = co_base + wco + tm * 16 + quad * 4;
        float4 bias = *(const float4*)&b1f[cog];
        float bb[4] = {bias.x, bias.y, bias.z, bias.w};
#pragma unroll
        for (int tn = 0; tn < 4; ++tn) {
            int sp = sp_base + wsp + tn * 16 + col;
            u16x4 oh, ol;
#pragma unroll
            for (int r = 0; r < 4; ++r) {
                float v = acc[tm][tn][r] + bb[r];
                v = v > 0.f ? v : 0.2f * v;
                u16 hh, ll; split2(v, hh, ll);
                oh[r] = hh; ol[r] = ll;
            }
            *(u16x4*)&a1h[((size_t)sp << 8) + cog] = oh;
            *(u16x4*)&a1l[((size_t)sp << 8) + cog] = ol;
        }
    }
}

__global__ __launch_bounds__(256, 2) void conv1_kernel(
        const u16* __restrict__ xh, const u16* __restrict__ xl,
        const u16* __restrict__ w1h, const u16* __restrict__ w1l,
        const float* __restrict__ b1f, u16* __restrict__ a1h, u16* __restrict__ a1l,
        const int* __restrict__ flagp) {
    __shared__ u16 Ah[2 * 128 * LDK];
    __shared__ u16 Al[2 * 128 * LDK];
    __shared__ u16 Bh[2 * 128 * LDK];
    __shared__ u16 Bl[2 * 128 * LDK];
    if (flagp[0]) conv1_body<true >(xh, xl, w1h, w1l, b1f, a1h, a1l, Ah, Al, Bh, Bl);
    else          conv1_body<false>(xh, xl, w1h, w1l, b1f, a1h, a1l, Ah, Al, Bh, Bl);
}

// conv2: tile 64x128, BK=32, two-barrier T14, single-buffered (round-10
// proven). NEW: nested p x unrolled kc with +1 lookahead prefetch.
#define C2_LOADP(P_, KC_, RAH, RAL, RBH0, RBH1, RBL0, RBL1) {                  \
    int ci0_ = (KC_) * 32;                                                     \
    const u16* wh_ = ((P_) < 9) ? w2h + (size_t)(P_) * 131072 : wsh;           \
    const u16* wl_ = ((P_) < 9) ? w2l + (size_t)(P_) * 131072 : wsl;           \
    size_t gs_ = (size_t)(co_base + ra) * 256 + ci0_ + ka;                     \
    RAH = *(const ushort8*)&wh_[gs_];                                          \
    if (DOLO) RAL = *(const ushort8*)&wl_[gs_];                                \
    const u16 *sh_, *sl_; size_t g_;                                           \
    if ((P_) < 9) {                                                            \
        int ky_ = (P_) / 3, kx_ = (P_) % 3;                                    \
        int yi_ = 2 * (yo0 + (r_st >> 5)) + ky_;                               \
        int xi_ = 2 * (r_st & 31) + kx_;                                       \
        g_ = (size_t)((n * 65 + yi_) * 65 + xi_) * 256 + ci0_ + k_st;          \
        sh_ = bl1h; sl_ = bl1l;                                                \
    } else {                                                                   \
        g_ = ((size_t)(sp_base + r_st) << 8) + ci0_ + k_st;                    \
        sh_ = skh; sl_ = skl;                                                  \
    }                                                                          \
    RBH0 = *(const ushort8*)&sh_[g_];                                          \
    RBH1 = *(const ushort8*)&sh_[g_ + 8];                                      \
    if (DOLO) { RBL0 = *(const ushort8*)&sl_[g_];                              \
                RBL1 = *(const ushort8*)&sl_[g_ + 8]; }                        \
}

template <bool DOLO>
__device__ __forceinline__ void conv2_body(
        const u16* __restrict__ bl1h, const u16* __restrict__ bl1l,
        const u16* __restrict__ skh,  const u16* __restrict__ skl,
        const u16* __restrict__ w2h, const u16* __restrict__ w2l,
        const u16* __restrict__ wsh, const u16* __restrict__ wsl,
        const float* __restrict__ b2f_, void* __restrict__ out, int n0,
        u16* Ah, u16* Al, u16* Bh, u16* Bl, int flag) {
    int tid = threadIdx.x, lane = tid & 63, wid = tid >> 6;
    int col = lane & 15, quad = lane >> 4;
    int wco = (wid >> 1) * 32, wsp = (wid & 1) * 64;
    // 1-D grid, 512 blocks: img (XCD) | sp_in | co, co fastest.
    int b = blockIdx.x;
    int img    = b & 7;                      // image -> XCD pinned
    int r      = b >> 3;                     // 0..63
    int co_blk = r & 7;                      // co fastest: blur1 rows L2-hot
    int sp_in  = r >> 3;                     // 0..7
    int sp_base = img * 1024 + sp_in * 128;  // over 8*1024
    int co_base = co_blk * 64;
    int n   = img;
    int yo0 = sp_in * 4;
    int r_st = tid >> 1, k_st = (tid & 1) * 16;
    int ra = tid >> 2, ka = (tid & 3) * 8;

    f32x4 acc[2][4], accs[2][4];
#pragma unroll
    for (int i = 0; i < 2; ++i)
#pragma unroll
        for (int j = 0; j < 4; ++j) {
            acc[i][j]  = (f32x4){0.f, 0.f, 0.f, 0.f};
            accs[i][j] = (f32x4){0.f, 0.f, 0.f, 0.f};
        }

    ushort8 nAh, nAl, nBh0, nBh1, nBl0, nBl1;
    C2_LOADP(0, 0, nAh, nAl, nBh0, nBh1, nBl0, nBl1);

    for (int p = 0; p < 10; ++p) {
#pragma unroll
        for (int kc = 0; kc < 8; ++kc) {
            __syncthreads();
            *(ushort8*)&Ah[ra * LDK + ka] = nAh;
            if (DOLO) *(ushort8*)&Al[ra * LDK + ka] = nAl;
            *(ushort8*)&Bh[r_st * LDK + k_st]     = nBh0;
            *(ushort8*)&Bh[r_st * LDK + k_st + 8] = nBh1;
            if (DOLO) {
                *(ushort8*)&Bl[r_st * LDK + k_st]     = nBl0;
                *(ushort8*)&Bl[r_st * LDK + k_st + 8] = nBl1;
            }
            // prefetch (p,kc)+1 — compile-time boundary split
            if (kc < 7) {
                C2_LOADP(p, kc + 1, nAh, nAl, nBh0, nBh1, nBl0, nBl1);
            } else {
                int pp = (p < 9) ? p + 1 : 9;
                int kk = (p < 9) ? 0 : 7;            // tail clamps to (9,7)
                C2_LOADP(pp, kk, nAh, nAl, nBh0, nBh1, nBl0, nBl1);
            }
            tile_barrier();
            short8 ah[2], al[2];
#pragma unroll
            for (int tm = 0; tm < 2; ++tm) {
                ah[tm] = *(const short8*)&Ah[(wco + tm * 16 + col) * LDK + quad * 8];
                if (DOLO) al[tm] = *(const short8*)&Al[(wco + tm * 16 + col) * LDK + quad * 8];
            }
            if (p < 9) {
#pragma unroll
                for (int tn = 0; tn < 4; ++tn) {
                    short8 bh = *(const short8*)&Bh[(wsp + tn * 16 + col) * LDK + quad * 8];
                    short8 bl;
                    if (DOLO) bl = *(const short8*)&Bl[(wsp + tn * 16 + col) * LDK + quad * 8];
#pragma unroll
                    for (int tm = 0; tm < 2; ++tm) {
                        acc[tm][tn] = __builtin_amdgcn_mfma_f32_16x16x32_bf16(ah[tm], bh, acc[tm][tn], 0, 0, 0);
                        if (DOLO) {
                            acc[tm][tn] = __builtin_amdgcn_mfma_f32_16x16x32_bf16(ah[tm], bl, acc[tm][tn], 0, 0, 0);
                            acc[tm][tn] = __builtin_amdgcn_mfma_f32_16x16x32_bf16(al[tm], bh, acc[tm][tn], 0, 0, 0);
                        }
                    }
                }
            } else {
#pragma unroll
                for (int tn = 0; tn < 4; ++tn) {
                    short8 bh = *(const short8*)&Bh[(wsp + tn * 16 + col) * LDK + quad * 8];
                    short8 bl;
                    if (DOLO) bl = *(const short8*)&Bl[(wsp + tn * 16 + col) * LDK + quad * 8];
#pragma unroll
                    for (int tm = 0; tm < 2; ++tm) {
                        accs[tm][tn] = __builtin_amdgcn_mfma_f32_16x16x32_bf16(ah[tm], bh, accs[tm][tn], 0, 0, 0);
                        if (DOLO) {
                            accs[tm][tn] = __builtin_amdgcn_mfma_f32_16x16x32_bf16(ah[tm], bl, accs[tm][tn], 0, 0, 0);
                            accs[tm][tn] = __builtin_amdgcn_mfma_f32_16x16x32_bf16(al[tm], bh, accs[tm][tn], 0, 0, 0);
                        }
                    }
                }
            }
        }
    }
    const float RS2 = 0.70710678118654752f;
#pragma unroll
    for (int tm = 0; tm < 2; ++tm) {
        int cog = co_base + wco + tm * 16 + quad * 4;
        float4 bias = *(const float4*)&b2f_[cog];
        float bb[4] = {bias.x, bias.y, bias.z, bias.w};
#pragma unroll
        for (int tn = 0; tn < 4; ++tn) {
            int sp  = sp_base + wsp + tn * 16 + col;
            int ng  = n0 + (sp >> 10);
            int rem = sp & 1023;
            size_t ob = ((size_t)ng * 512 + cog) * 1024 + rem;
#pragma unroll
            for (int r2 = 0; r2 < 4; ++r2) {
                float v = acc[tm][tn][r2] + bb[r2];
                v = v > 0.f ? v : 0.2f * v;
                v = (v + accs[tm][tn][r2]) * RS2;
                if (flag) ((float*)out)[ob + (size_t)r2 * 1024] = v;
                else      ((u16*)out)[ob + (size_t)r2 * 1024]   = f2b(v);
            }
        }
    }
}

__global__ __launch_bounds__(256, 2) void conv2_kernel(
        const u16* __restrict__ bl1h, const u16* __restrict__ bl1l,
        const u16* __restrict__ skh,  const u16* __restrict__ skl,
        const u16* __restrict__ w2h, const u16* __restrict__ w2l,
        const u16* __restrict__ wsh, const u16* __restrict__ wsl,
        const float* __restrict__ b2f_, const int* __restrict__ flagp,
        void* __restrict__ out, int n0) {
    __shared__ u16 Ah[64 * LDK];
    __shared__ u16 Al[64 * LDK];
    __shared__ u16 Bh[128 * LDK];
    __shared__ u16 Bl[128 * LDK];
    int flag = flagp[0];
    if (flag) conv2_body<true >(bl1h, bl1l, skh, skl, w2h, w2l, wsh, wsl, b2f_, out, n0, Ah, Al, Bh, Bl, flag);
    else      conv2_body<false>(bl1h, bl1l, skh, skl, w2h, w2l, wsh, wsl, b2f_, out, n0, Ah, Al, Bh, Bl, flag);
}

// ---------------------------------------------------------------------------
// Workspace (bytes), total 84,160,512 (same proven footprint):
//   0        flag | 64 inv_sigma
//   1024     b1f  | 2048 b2f
//   4096     w1h  | 1183744 w1l | 2363392 w2h | 4722688 w2l | 7081984 wsh | 7344128 wsl
//   7606272  xt hi/lo planes (16,777,216 each) — aliased after conv1 by blur1
//            hi/lo planes (17,305,600 each); sigma scratch aliased at head
//   42217472 act1 hi/lo bf16 planes (16,777,216 each)
//   75771904 skipin hi/lo planes (4,194,304 each)
// ---------------------------------------------------------------------------
extern "C" void kernel_launch(void* const* d_in, const int* in_sizes, int n_in,
                              void* d_out, int out_size, void* d_ws, size_t ws_size,
                              hipStream_t stream) {
    const void* x   = d_in[0];
    const void* w1b = d_in[1];
    const void* u1  = d_in[2];
    const void* b1  = d_in[4];
    const void* w2b = d_in[5];
    const void* u2  = d_in[6];
    const void* b2  = d_in[8];
    const void* wsb = d_in[9];
    const void* us  = d_in[10];

    char* ws = (char*)d_ws;
    int*   flag      = (int*)(ws);
    float* inv_sigma = (float*)(ws + 64);
    float* b1f       = (float*)(ws + 1024);
    float* b2fp      = (float*)(ws + 2048);
    u16* w1h = (u16*)(ws + 4096);
    u16* w1l = (u16*)(ws + 1183744);
    u16* w2h = (u16*)(ws + 2363392);
    u16* w2l = (u16*)(ws + 4722688);
    u16* wsh = (u16*)(ws + 7081984);
    u16* wsl = (u16*)(ws + 7344128);
    u16* xth  = (u16*)(ws + 7606272);
    u16* xtl  = (u16*)(ws + 7606272 + 16777216);
    u16* bl1h = (u16*)(ws + 7606272);                 // aliased: xt dead after conv1
    u16* bl1l = (u16*)(ws + 7606272 + 17305600);
    u16* a1h = (u16*)(ws + 42217472);
    u16* a1l = (u16*)(ws + 42217472 + 16777216);
    u16* skh = (u16*)(ws + 75771904);
    u16* skl = (u16*)(ws + 75771904 + 4194304);
    // sigma scratch aliased into the head of the xt region (dead before transpose)
    float* tvec  = (float*)(ws + 7606272);            // 4864 floats
    float* ntinv = (float*)(ws + 7606272 + 19456);
    float* ns    = (float*)(ws + 7606272 + 19520);

    detect_kernel<<<1, 256, 0, stream>>>((const unsigned*)x, flag);
    sig_init_kernel<<<19, 256, 0, stream>>>(tvec, ns);
    sig_t_kernel<<<116, 256, 0, stream>>>(w1b, u1, w2b, u2, wsb, us, flag, tvec);
    sig_norm_kernel<<<3, 256, 0, stream>>>(tvec, ntinv);
    sig_s_kernel<<<320, 256, 0, stream>>>(w1b, w2b, wsb, flag, tvec, ntinv, ns);
    sig_fin_kernel<<<1, 64, 0, stream>>>(ns, inv_sigma);
    wprep_kernel<<<7427, 256, 0, stream>>>(w1b, w2b, wsb, b1, b2, inv_sigma, flag,
                                           w1h, w1l, w2h, w2l, wsh, wsl, b1f, b2fp);
    for (int c = 0; c < 2; ++c) {
        int n0 = c * 8;
        transpose_kernel<<<dim3(512, 8), 256, 0, stream>>>(x, xth, xtl, flag, n0);
        blursample_kernel<<<1024, 256, 0, stream>>>(xth, xtl, skh, skl);
        conv1_kernel<<<dim3(256, 2), 256, 0, stream>>>(xth, xtl, w1h, w1l, b1f, a1h, a1l, flag);
        blur1_kernel<<<4225, 256, 0, stream>>>(a1h, a1l, bl1h, bl1l);
        conv2_kernel<<<512, 256, 0, stream>>>(bl1h, bl1l, skh, skl, w2h, w2l,
                                              wsh, wsl, b2fp, flag, d_out, n0);
    }
}

// Round 14
// 649.972 us; speedup vs baseline: 1.0298x; 1.0298x over previous
//
#include <hip/hip_runtime.h>
#include <math.h>

typedef unsigned short u16;
typedef __attribute__((ext_vector_type(8))) unsigned short ushort8;
typedef __attribute__((ext_vector_type(4))) unsigned short u16x4;
typedef __attribute__((ext_vector_type(8))) short short8;
typedef __attribute__((ext_vector_type(4))) float f32x4;

__device__ __forceinline__ float b2f(u16 v) {
    unsigned u = ((unsigned)v) << 16; float f; __builtin_memcpy(&f, &u, 4); return f;
}
__device__ __forceinline__ u16 f2b(float f) {
    unsigned u; __builtin_memcpy(&u, &f, 4);
    u = (u + 0x7fffu + ((u >> 16) & 1u)) >> 16;   // RNE
    return (u16)u;
}
// flag-branched raw-input load (flag: 1 = fp32 inputs, 0 = bf16 inputs)
__device__ __forceinline__ float ldin(const void* p, int i, int flag) {
    return flag ? ((const float*)p)[i] : b2f(((const u16*)p)[i]);
}
__device__ __forceinline__ void split2(float x, u16& h, u16& l) {
    h = f2b(x);
    l = f2b(x - b2f(h));
}
__device__ __forceinline__ ushort8 zero8() {
    ushort8 z;
#pragma unroll
    for (int i = 0; i < 8; ++i) z[i] = 0;
    return z;
}
// Non-draining tile barrier: flush own LDS writes (lgkmcnt only), raw
// s_barrier. Prefetch global loads (vmcnt) stay IN FLIGHT across it.
__device__ __forceinline__ void tile_barrier() {
    asm volatile("s_waitcnt lgkmcnt(0)" ::: "memory");
    __builtin_amdgcn_s_barrier();
    asm volatile("" ::: "memory");
}

// ---------------------------------------------------------------------------
// dtype detector: fp32 N(0,1) words have exponent field in [77,157];
// bf16 pairs viewed as fp32 essentially never do. flag=1 -> fp32.
// ---------------------------------------------------------------------------
__global__ void detect_kernel(const unsigned* __restrict__ xw, int* __restrict__ flag) {
    __shared__ int red[4];
    int tid = threadIdx.x, lane = tid & 63, wid = tid >> 6;
    int cnt = 0;
    for (int i = 0; i < 16; ++i) {
        unsigned w = xw[tid * 16 + i];
        unsigned e = (w >> 23) & 0xFF;
        if (e >= 77u && e <= 157u) ++cnt;
    }
    for (int o = 32; o; o >>= 1) cnt += __shfl_down(cnt, o, 64);
    if (lane == 0) red[wid] = cnt;
    __syncthreads();
    if (tid == 0) flag[0] = (red[0] + red[1] + red[2] + red[3] >= 2048) ? 1 : 0;
}

// ---------------------------------------------------------------------------
// Parallel spectral norm. t layout: [0]=t1(2304) [2304]=t2(2304) [4608]=ts(256)
// ---------------------------------------------------------------------------
__global__ void sig_init_kernel(float* __restrict__ t, float* __restrict__ ns) {
    int i = blockIdx.x * 256 + threadIdx.x;
    if (i < 4864) t[i] = 0.f;
    if (i < 3) ns[i] = 0.f;
}

// t = W^T u, grid-parallel over (weight, j-chunk of 256, i-chunk of 64)
__global__ void sig_t_kernel(const void* __restrict__ w1, const void* __restrict__ u1,
                             const void* __restrict__ w2, const void* __restrict__ u2,
                             const void* __restrict__ wsb, const void* __restrict__ us,
                             const int* __restrict__ flagp, float* __restrict__ t) {
    __shared__ float ush[64];
    int blk = blockIdx.x;
    int flag = flagp[0];
    const void* W; const void* U; int m, toff, jc, ic;
    if (blk < 36)       { W = w1;  U = u1; m = 2304; toff = 0;    jc = blk % 9; ic = blk / 9; }
    else if (blk < 108) { int r = blk - 36;  W = w2;  U = u2; m = 2304; toff = 2304; jc = r % 9; ic = r / 9; }
    else                { int r = blk - 108; W = wsb; U = us; m = 256;  toff = 4608; jc = 0;     ic = r; }
    int tid = threadIdx.x;
    if (tid < 64) ush[tid] = ldin(U, ic * 64 + tid, flag);
    __syncthreads();
    int j = jc * 256 + tid;
    float acc = 0.f;
    int base = ic * 64 * m + j;
    for (int ii = 0; ii < 64; ++ii) acc += ldin(W, base + ii * m, flag) * ush[ii];
    atomicAdd(&t[toff + j], acc);
}

__global__ void sig_norm_kernel(float* __restrict__ t, float* __restrict__ ntinv) {
    __shared__ float red[4];
    int b = blockIdx.x;
    int m = (b == 2) ? 256 : 2304;
    int toff = b * 2304;
    int tid = threadIdx.x, lane = tid & 63, wid = tid >> 6;
    float s = 0.f;
    for (int j = tid; j < m; j += 256) { float v = t[toff + j]; s += v * v; }
    for (int o = 32; o; o >>= 1) s += __shfl_down(s, o, 64);
    if (lane == 0) red[wid] = s;
    __syncthreads();
    if (tid == 0) ntinv[b] = 1.f / (sqrtf(red[0] + red[1] + red[2] + red[3]) + 1e-12f);
}

// s_i = (W t)_i * ntinv ; ns_b += s_i^2. One wave per row.
__global__ void sig_s_kernel(const void* __restrict__ w1, const void* __restrict__ w2,
                             const void* __restrict__ wsb, const int* __restrict__ flagp,
                             const float* __restrict__ t, const float* __restrict__ ntinv,
                             float* __restrict__ ns) {
    int flag = flagp[0];
    int wg = blockIdx.x * 4 + (threadIdx.x >> 6);   // 0..1279
    int lane = threadIdx.x & 63;
    const void* W; int m, toff, i, b;
    if (wg < 256)      { W = w1;  m = 2304; toff = 0;    i = wg;       b = 0; }
    else if (wg < 768) { W = w2;  m = 2304; toff = 2304; i = wg - 256; b = 1; }
    else               { W = wsb; m = 256;  toff = 4608; i = wg - 768; b = 2; }
    float acc = 0.f;
    int base = i * m;
    for (int j = lane; j < m; j += 64) acc += ldin(W, base + j, flag) * t[toff + j];
    for (int o = 32; o; o >>= 1) acc += __shfl_down(acc, o, 64);
    if (lane == 0) { float s = acc * ntinv[b]; atomicAdd(&ns[b], s * s); }
}

__global__ void sig_fin_kernel(const float* __restrict__ ns, float* __restrict__ inv_sigma) {
    int b = threadIdx.x;
    if (b < 3) { float s2 = ns[b]; float s = sqrtf(s2); inv_sigma[b] = (s + 1e-12f) / s2; }
}

// ---------------------------------------------------------------------------
// Weight prep: scale by 1/sigma, transpose to [kyx][co][ci], split hi/lo.
// Also canonicalizes biases to fp32.
// ---------------------------------------------------------------------------
__global__ void wprep_kernel(const void* __restrict__ w1b, const void* __restrict__ w2b,
                             const void* __restrict__ wsb,
                             const void* __restrict__ b1,  const void* __restrict__ b2,
                             const float* __restrict__ inv_sigma, const int* __restrict__ flagp,
                             u16* __restrict__ w1h, u16* __restrict__ w1l,
                             u16* __restrict__ w2h, u16* __restrict__ w2l,
                             u16* __restrict__ wsh, u16* __restrict__ wsl,
                             float* __restrict__ b1f, float* __restrict__ b2f_) {
    int idx = blockIdx.x * 256 + threadIdx.x;
    int flag = flagp[0];
    float s0 = inv_sigma[0], s1 = inv_sigma[1], s2 = inv_sigma[2];
    if (idx < 589824) {                       // 9*256*256
        int kyx = idx / 65536; int rem = idx - kyx * 65536;
        int co = rem >> 8, ci = rem & 255;
        float w = ldin(w1b, ((co << 8) + ci) * 9 + kyx, flag) * s0;
        split2(w, w1h[idx], w1l[idx]);
    } else if (idx < 589824 + 1179648) {      // 9*512*256
        int i2 = idx - 589824;
        int kyx = i2 / 131072; int rem = i2 - kyx * 131072;
        int co = rem >> 8, ci = rem & 255;
        float w = ldin(w2b, ((co << 8) + ci) * 9 + kyx, flag) * s1;
        split2(w, w2h[i2], w2l[i2]);
    } else if (idx < 1900544) {               // 512*256
        int i3 = idx - 1769472;
        float w = ldin(wsb, i3, flag) * s2;
        split2(w, wsh[i3], wsl[i3]);
    } else if (idx < 1900544 + 256) {
        b1f[idx - 1900544] = ldin(b1, idx - 1900544, flag);
    } else if (idx < 1900544 + 768) {
        b2f_[idx - 1900800] = ldin(b2, idx - 1900800, flag);
    }
}

// ---------------------------------------------------------------------------
// x NCHW -> xt bf16-hi/lo NHWC planes for one 8-image chunk.
// Vectorized input path: branch once on flag, float4/ushort8 loads.
// ---------------------------------------------------------------------------
__global__ void transpose_kernel(const void* __restrict__ x, u16* __restrict__ xh,
                                 u16* __restrict__ xl,
                                 const int* __restrict__ flagp, int n0) {
    __shared__ float tile[32][65];
    int flag = flagp[0];
    int ny  = blockIdx.x;                    // nl*64 + y
    int ci0 = blockIdx.y * 32;
    int nl = ny >> 6, y = ny & 63;
    int t = threadIdx.x;
    int ci_l = t >> 3, x8 = (t & 7) * 8;
    int base = ((n0 + nl) * 256 + ci0 + ci_l) * 4096 + y * 64 + x8;
    if (flag) {
        const float* xf = (const float*)x;
        float4 v0 = *(const float4*)&xf[base];
        float4 v1 = *(const float4*)&xf[base + 4];
        tile[ci_l][x8 + 0] = v0.x; tile[ci_l][x8 + 1] = v0.y;
        tile[ci_l][x8 + 2] = v0.z; tile[ci_l][x8 + 3] = v0.w;
        tile[ci_l][x8 + 4] = v1.x; tile[ci_l][x8 + 5] = v1.y;
        tile[ci_l][x8 + 6] = v1.z; tile[ci_l][x8 + 7] = v1.w;
    } else {
        const u16* xb = (const u16*)x;
        ushort8 v = *(const ushort8*)&xb[base];
#pragma unroll
        for (int k = 0; k < 8; ++k) tile[ci_l][x8 + k] = b2f(v[k]);
    }
    __syncthreads();
    int x_l = t >> 2, oc = (t & 3) * 8;
    size_t o = ((size_t)ny * 64 + x_l) * 256 + ci0 + oc;
    ushort8 h, l;
#pragma unroll
    for (int k = 0; k < 8; ++k) {
        u16 hh, ll; split2(tile[oc + k][x_l], hh, ll);
        h[k] = hh; l[k] = ll;
    }
    *(ushort8*)&xh[o] = h;
    *(ushort8*)&xl[o] = l;
}

__device__ __constant__ float BW[4] = {0.125f, 0.375f, 0.375f, 0.125f};

// ---------------------------------------------------------------------------
// blur of act1 (bf16 hi/lo NHWC 64x64, 8 images) pad(2,2) -> blur1 hi/lo.
// 4 y-outputs per thread: x-blur 8 input rows once into regs (row reuse:
// adjacent outputs share 3 of 4 y-taps) -> 2x fewer loads than 1-output.
// 8 channels/thread, 16B ushort8 loads.
// ---------------------------------------------------------------------------
__global__ void blur1_kernel(const u16* __restrict__ a1h, const u16* __restrict__ a1l,
                             u16* __restrict__ bh, u16* __restrict__ bl) {
    int idx = blockIdx.x * 256 + threadIdx.x;     // 8 n * 17 yt * 65 xq * 32 chg
    int ch = (idx & 31) * 8;
    int rem = idx >> 5;
    int xq = rem % 65; rem /= 65;
    int yt = rem % 17;
    int n  = rem / 17;
    int yq0 = yt * 4;
    float rb[8][8];                                // x-blurred rows yq0-2..yq0+5
#pragma unroll
    for (int r = 0; r < 8; ++r) {
        int yy = yq0 + r - 2;
#pragma unroll
        for (int k = 0; k < 8; ++k) rb[r][k] = 0.f;
        if ((unsigned)yy < 64u) {
#pragma unroll
            for (int j = 0; j < 4; ++j) {
                int xx = xq + j - 2;
                if ((unsigned)xx >= 64u) continue;
                float w = BW[j];
                size_t g = ((size_t)((n * 64 + yy) * 64 + xx) << 8) + ch;
                ushort8 vh = *(const ushort8*)&a1h[g];
                ushort8 vl = *(const ushort8*)&a1l[g];
#pragma unroll
                for (int k = 0; k < 8; ++k) rb[r][k] += w * (b2f(vh[k]) + b2f(vl[k]));
            }
        }
    }
#pragma unroll
    for (int ko = 0; ko < 4; ++ko) {
        int yq = yq0 + ko;
        if (yq > 64) continue;
        ushort8 h, l;
#pragma unroll
        for (int k = 0; k < 8; ++k) {
            float a = BW[0] * rb[ko][k] + BW[1] * rb[ko + 1][k]
                    + BW[2] * rb[ko + 2][k] + BW[3] * rb[ko + 3][k];
            u16 hh, ll; split2(a, hh, ll);
            h[k] = hh; l[k] = ll;
        }
        size_t o = ((size_t)((n * 65 + yq) * 65 + xq) << 8) + ch;
        *(ushort8*)&bh[o] = h;
        *(ushort8*)&bl[o] = l;
    }
}

// ---------------------------------------------------------------------------
// skip blur of xt (hi/lo planes) pad(1,1) at even pos -> skipin hi/lo planes.
// 8 channels/thread, 16B loads.
// ---------------------------------------------------------------------------
__global__ void blursample_kernel(const u16* __restrict__ xh, const u16* __restrict__ xl,
                                  u16* __restrict__ sh, u16* __restrict__ sl) {
    int idx = blockIdx.x * 256 + threadIdx.x;     // 8*32*32*32
    int ch = (idx & 31) * 8;
    int rem = idx >> 5;
    int xo = rem & 31;
    int yo = (rem >> 5) & 31;
    int n  = rem >> 10;
    float acc[8];
#pragma unroll
    for (int k = 0; k < 8; ++k) acc[k] = 0.f;
#pragma unroll
    for (int i = 0; i < 4; ++i) {
        int yy = 2 * yo + i - 1;
        if ((unsigned)yy >= 64u) continue;
#pragma unroll
        for (int j = 0; j < 4; ++j) {
            int xx = 2 * xo + j - 1;
            if ((unsigned)xx >= 64u) continue;
            float w = BW[i] * BW[j];
            size_t g = ((size_t)((n * 64 + yy) * 64 + xx) << 8) + ch;
            ushort8 vh = *(const ushort8*)&xh[g];
            ushort8 vl = *(const ushort8*)&xl[g];
#pragma unroll
            for (int k = 0; k < 8; ++k) acc[k] += w * (b2f(vh[k]) + b2f(vl[k]));
        }
    }
    ushort8 h, l;
#pragma unroll
    for (int k = 0; k < 8; ++k) {
        u16 hh, ll; split2(acc[k], hh, ll);
        h[k] = hh; l[k] = ll;
    }
    size_t o = ((size_t)((n * 32 + yo) * 32 + xo) << 8) + ch;
    *(ushort8*)&sh[o] = h;
    *(ushort8*)&sl[o] = l;
}

// ---------------------------------------------------------------------------
// conv1 (round-11/12 proven, 127.5 us): tile 128x128, BK=32, LDS dbuf,
// ONE non-draining barrier/iter, pure-reg MFMA burst with setprio.
// ---------------------------------------------------------------------------
#define LDK 40
#define C1_HALF (128 * LDK)

#define C1_LOAD(IT, RAH0, RAH1, RAL0, RAL1, RBH0, RBH1, RBL0, RBL1) {          \
    int p_ = (IT) >> 3, kc_ = (IT) & 7;                                        \
    const u16* wh_ = w1h + (size_t)p_ * 65536;                                 \
    const u16* wl_ = w1l + (size_t)p_ * 65536;                                 \
    size_t gs_ = (size_t)(co_base + ra) * 256 + kc_ * 32 + ka;                 \
    RAH0 = *(const ushort8*)&wh_[gs_];                                         \
    RAH1 = *(const ushort8*)&wh_[gs_ + 8];                                     \
    if (DOLO) { RAL0 = *(const ushort8*)&wl_[gs_];                             \
                RAL1 = *(const ushort8*)&wl_[gs_ + 8]; }                       \
    int dy_ = p_ / 3 - 1, dx_ = p_ % 3 - 1;                                    \
    int yy_ = y0 + (ra >> 6) + dy_, xx_ = (ra & 63) + dx_;                     \
    if ((unsigned)yy_ < 64u && (unsigned)xx_ < 64u) {                          \
        size_t g_ = ((size_t)((n * 64 + yy_) * 64 + xx_) << 8) + kc_ * 32 + ka;\
        RBH0 = *(const ushort8*)&xh[g_];                                       \
        RBH1 = *(const ushort8*)&xh[g_ + 8];                                   \
        if (DOLO) { RBL0 = *(const ushort8*)&xl[g_];                           \
                    RBL1 = *(const ushort8*)&xl[g_ + 8]; }                     \
    } else {                                                                   \
        RBH0 = zero8(); RBH1 = zero8();                                        \
        if (DOLO) { RBL0 = zero8(); RBL1 = zero8(); }                          \
    }                                                                          \
}

#define C1_WRITE(OFF) {                                                        \
    *(ushort8*)&Ah[(OFF) + ra * LDK + ka]     = nAh0;                          \
    *(ushort8*)&Ah[(OFF) + ra * LDK + ka + 8] = nAh1;                          \
    if (DOLO) {                                                                \
        *(ushort8*)&Al[(OFF) + ra * LDK + ka]     = nAl0;                      \
        *(ushort8*)&Al[(OFF) + ra * LDK + ka + 8] = nAl1;                      \
    }                                                                          \
    *(ushort8*)&Bh[(OFF) + ra * LDK + ka]     = nBh0;                          \
    *(ushort8*)&Bh[(OFF) + ra * LDK + ka + 8] = nBh1;                          \
    if (DOLO) {                                                                \
        *(ushort8*)&Bl[(OFF) + ra * LDK + ka]     = nBl0;                      \
        *(ushort8*)&Bl[(OFF) + ra * LDK + ka + 8] = nBl1;                      \
    }                                                                          \
}

template <bool DOLO>
__device__ __forceinline__ void conv1_body(
        const u16* __restrict__ xh, const u16* __restrict__ xl,
        const u16* __restrict__ w1h, const u16* __restrict__ w1l,
        const float* __restrict__ b1f, u16* __restrict__ a1h, u16* __restrict__ a1l,
        u16* Ah, u16* Al, u16* Bh, u16* Bl) {
    int tid = threadIdx.x, lane = tid & 63, wid = tid >> 6;
    int col = lane & 15, quad = lane >> 4;
    int wco = (wid >> 1) * 64, wsp = (wid & 1) * 64;
    int bidx = blockIdx.x;                         // 256 sp blocks
    int sp_blk = (bidx & 7) * 32 + (bidx >> 3);    // XCD swizzle: image-per-XCD
    int sp_base = sp_blk * 128;                    // over 8*4096 (2 rows/tile)
    int co_base = blockIdx.y * 128;
    int n  = sp_base >> 12;
    int y0 = (sp_base & 4095) >> 6;
    int ra = tid >> 1, ka = (tid & 1) * 16;        // A & B staging: 128 rows x 2 slots

    f32x4 acc[4][4];
#pragma unroll
    for (int i = 0; i < 4; ++i)
#pragma unroll
        for (int j = 0; j < 4; ++j) acc[i][j] = (f32x4){0.f, 0.f, 0.f, 0.f};

    ushort8 nAh0, nAh1, nAl0, nAl1, nBh0, nBh1, nBl0, nBl1;
    // prologue: stage it=0 into buf0, prefetch it=1
    C1_LOAD(0, nAh0, nAh1, nAl0, nAl1, nBh0, nBh1, nBl0, nBl1);
    C1_WRITE(0);
    C1_LOAD(1, nAh0, nAh1, nAl0, nAl1, nBh0, nBh1, nBl0, nBl1);
    tile_barrier();

    for (int it = 0; it < 72; ++it) {
        const int cur = (it & 1) ? C1_HALF : 0;
        const int nxt = (it & 1) ? 0 : C1_HALF;
        // read ALL fragments from current buffer (pure-reg MFMA burst after)
        short8 ah[4], al[4], bhf[4], blf[4];
#pragma unroll
        for (int tm = 0; tm < 4; ++tm) {
            ah[tm] = *(const short8*)&Ah[cur + (wco + tm * 16 + col) * LDK + quad * 8];
            if (DOLO) al[tm] = *(const short8*)&Al[cur + (wco + tm * 16 + col) * LDK + quad * 8];
        }
#pragma unroll
        for (int tn = 0; tn < 4; ++tn) {
            bhf[tn] = *(const short8*)&Bh[cur + (wsp + tn * 16 + col) * LDK + quad * 8];
            if (DOLO) blf[tn] = *(const short8*)&Bl[cur + (wsp + tn * 16 + col) * LDK + quad * 8];
        }
        // write NEXT tile (regs hold it+1's data, loads issued last iter)
        C1_WRITE(nxt);
        // prefetch it+2
        int itn = (it + 2 < 72) ? it + 2 : 71;
        C1_LOAD(itn, nAh0, nAh1, nAl0, nAl1, nBh0, nBh1, nBl0, nBl1);
        __builtin_amdgcn_s_setprio(1);
#pragma unroll
        for (int tn = 0; tn < 4; ++tn)
#pragma unroll
            for (int tm = 0; tm < 4; ++tm) {
                acc[tm][tn] = __builtin_amdgcn_mfma_f32_16x16x32_bf16(ah[tm], bhf[tn], acc[tm][tn], 0, 0, 0);
                if (DOLO) {
                    acc[tm][tn] = __builtin_amdgcn_mfma_f32_16x16x32_bf16(ah[tm], blf[tn], acc[tm][tn], 0, 0, 0);
                    acc[tm][tn] = __builtin_amdgcn_mfma_f32_16x16x32_bf16(al[tm], bhf[tn], acc[tm][tn], 0, 0, 0);
                }
            }
        __builtin_amdgcn_s_setprio(0);
        tile_barrier();                            // one barrier/iter; loads fly
    }
#pragma unroll
    for (int tm = 0; tm < 4; ++tm) {
        int cog = co_base + wco + tm * 16 + quad * 4;
        float4 bias = *(const float4*)&b1f[cog];
        float bb[4] = {bias.x, bias.y, bias.z, bias.w};
#pragma unroll
        for (int tn = 0; tn < 4; ++tn) {
            int sp = sp_base + wsp + tn * 16 + col;
            u16x4 oh, ol;
#pragma unroll
            for (int r = 0; r < 4; ++r) {
                float v = acc[tm][tn][r] + bb[r];
                v = v > 0.f ? v : 0.2f * v;
                u16 hh, ll; split2(v, hh, ll);
                oh[r] = hh; ol[r] = ll;
            }
            *(u16x4*)&a1h[((size_t)sp << 8) + cog] = oh;
            *(u16x4*)&a1l[((size_t)sp << 8) + cog] = ol;
        }
    }
}

__global__ __launch_bounds__(256, 2) void conv1_kernel(
        const u16* __restrict__ xh, const u16* __restrict__ xl,
        const u16* __restrict__ w1h, const u16* __restrict__ w1l,
        const float* __restrict__ b1f, u16* __restrict__ a1h, u16* __restrict__ a1l,
        const int* __restrict__ flagp) {
    __shared__ u16 Ah[2 * 128 * LDK];
    __shared__ u16 Al[2 * 128 * LDK];
    __shared__ u16 Bh[2 * 128 * LDK];
    __shared__ u16 Bl[2 * 128 * LDK];
    if (flagp[0]) conv1_body<true >(xh, xl, w1h, w1l, b1f, a1h, a1l, Ah, Al, Bh, Bl);
    else          conv1_body<false>(xh, xl, w1h, w1l, b1f, a1h, a1l, Ah, Al, Bh, Bl);
}

// conv2 (round-10/12 proven): tile 64x128, BK=32, 80 iterations, two-barrier
// T14 async-stage, single-buffered LDS. 1-D grid with image->XCD pinning,
// co fastest.
#define C2_LOAD(IT, RAH, RAL, RBH0, RBH1, RBL0, RBL1) {                        \
    int p_ = (IT) >> 3, kc_ = (IT) & 7; int ci0_ = kc_ * 32;                   \
    const u16* wh_ = (p_ < 9) ? w2h + (size_t)p_ * 131072 : wsh;               \
    const u16* wl_ = (p_ < 9) ? w2l + (size_t)p_ * 131072 : wsl;               \
    size_t gs_ = (size_t)(co_base + ra) * 256 + ci0_ + ka;                     \
    RAH = *(const ushort8*)&wh_[gs_];                                          \
    if (DOLO) RAL = *(const ushort8*)&wl_[gs_];                                \
    const u16 *sh_, *sl_; size_t g_;                                           \
    if (p_ < 9) {                                                              \
        int ky_ = p_ / 3, kx_ = p_ % 3;                                        \
        int yi_ = 2 * (yo0 + (r_st >> 5)) + ky_;                               \
        int xi_ = 2 * (r_st & 31) + kx_;                                       \
        g_ = (size_t)((n * 65 + yi_) * 65 + xi_) * 256 + ci0_ + k_st;          \
        sh_ = bl1h; sl_ = bl1l;                                                \
    } else {                                                                   \
        g_ = ((size_t)(sp_base + r_st) << 8) + ci0_ + k_st;                    \
        sh_ = skh; sl_ = skl;                                                  \
    }                                                                          \
    RBH0 = *(const ushort8*)&sh_[g_];                                          \
    RBH1 = *(const ushort8*)&sh_[g_ + 8];                                      \
    if (DOLO) { RBL0 = *(const ushort8*)&sl_[g_];                              \
                RBL1 = *(const ushort8*)&sl_[g_ + 8]; }                        \
}

template <bool DOLO>
__device__ __forceinline__ void conv2_body(
        const u16* __restrict__ bl1h, const u16* __restrict__ bl1l,
        const u16* __restrict__ skh,  const u16* __restrict__ skl,
        const u16* __restrict__ w2h, const u16* __restrict__ w2l,
        const u16* __restrict__ wsh, const u16* __restrict__ wsl,
        const float* __restrict__ b2f_, void* __restrict__ out, int n0,
        u16* Ah, u16* Al, u16* Bh, u16* Bl, int flag) {
    int tid = threadIdx.x, lane = tid & 63, wid = tid >> 6;
    int col = lane & 15, quad = lane >> 4;
    int wco = (wid >> 1) * 32, wsp = (wid & 1) * 64;
    // 1-D grid, 512 blocks: img (XCD) | sp_in | co, co fastest.
    int b = blockIdx.x;
    int img    = b & 7;                      // image -> XCD pinned
    int r      = b >> 3;                     // 0..63
    int co_blk = r & 7;                      // co fastest: blur1 rows L2-hot
    int sp_in  = r >> 3;                     // 0..7
    int sp_base = img * 1024 + sp_in * 128;  // over 8*1024
    int co_base = co_blk * 64;
    int n   = img;
    int yo0 = sp_in * 4;
    int r_st = tid >> 1, k_st = (tid & 1) * 16;
    int ra = tid >> 2, ka = (tid & 3) * 8;

    f32x4 acc[2][4], accs[2][4];
#pragma unroll
    for (int i = 0; i < 2; ++i)
#pragma unroll
        for (int j = 0; j < 4; ++j) {
            acc[i][j]  = (f32x4){0.f, 0.f, 0.f, 0.f};
            accs[i][j] = (f32x4){0.f, 0.f, 0.f, 0.f};
        }

    ushort8 nAh, nAl, nBh0, nBh1, nBl0, nBl1;
    C2_LOAD(0, nAh, nAl, nBh0, nBh1, nBl0, nBl1);

    for (int it = 0; it < 80; ++it) {
        int p = it >> 3;
        __syncthreads();
        *(ushort8*)&Ah[ra * LDK + ka] = nAh;
        if (DOLO) *(ushort8*)&Al[ra * LDK + ka] = nAl;
        *(ushort8*)&Bh[r_st * LDK + k_st]     = nBh0;
        *(ushort8*)&Bh[r_st * LDK + k_st + 8] = nBh1;
        if (DOLO) {
            *(ushort8*)&Bl[r_st * LDK + k_st]     = nBl0;
            *(ushort8*)&Bl[r_st * LDK + k_st + 8] = nBl1;
        }
        int itn = (it + 1 < 80) ? it + 1 : it;
        C2_LOAD(itn, nAh, nAl, nBh0, nBh1, nBl0, nBl1);
        tile_barrier();
        short8 ah[2], al[2];
#pragma unroll
        for (int tm = 0; tm < 2; ++tm) {
            ah[tm] = *(const short8*)&Ah[(wco + tm * 16 + col) * LDK + quad * 8];
            if (DOLO) al[tm] = *(const short8*)&Al[(wco + tm * 16 + col) * LDK + quad * 8];
        }
        if (p < 9) {
#pragma unroll
            for (int tn = 0; tn < 4; ++tn) {
                short8 bh = *(const short8*)&Bh[(wsp + tn * 16 + col) * LDK + quad * 8];
                short8 bl;
                if (DOLO) bl = *(const short8*)&Bl[(wsp + tn * 16 + col) * LDK + quad * 8];
#pragma unroll
                for (int tm = 0; tm < 2; ++tm) {
                    acc[tm][tn] = __builtin_amdgcn_mfma_f32_16x16x32_bf16(ah[tm], bh, acc[tm][tn], 0, 0, 0);
                    if (DOLO) {
                        acc[tm][tn] = __builtin_amdgcn_mfma_f32_16x16x32_bf16(ah[tm], bl, acc[tm][tn], 0, 0, 0);
                        acc[tm][tn] = __builtin_amdgcn_mfma_f32_16x16x32_bf16(al[tm], bh, acc[tm][tn], 0, 0, 0);
                    }
                }
            }
        } else {
#pragma unroll
            for (int tn = 0; tn < 4; ++tn) {
                short8 bh = *(const short8*)&Bh[(wsp + tn * 16 + col) * LDK + quad * 8];
                short8 bl;
                if (DOLO) bl = *(const short8*)&Bl[(wsp + tn * 16 + col) * LDK + quad * 8];
#pragma unroll
                for (int tm = 0; tm < 2; ++tm) {
                    accs[tm][tn] = __builtin_amdgcn_mfma_f32_16x16x32_bf16(ah[tm], bh, accs[tm][tn], 0, 0, 0);
                    if (DOLO) {
                        accs[tm][tn] = __builtin_amdgcn_mfma_f32_16x16x32_bf16(ah[tm], bl, accs[tm][tn], 0, 0, 0);
                        accs[tm][tn] = __builtin_amdgcn_mfma_f32_16x16x32_bf16(al[tm], bh, accs[tm][tn], 0, 0, 0);
                    }
                }
            }
        }
    }
    const float RS2 = 0.70710678118654752f;
#pragma unroll
    for (int tm = 0; tm < 2; ++tm) {
        int cog = co_base + wco + tm * 16 + quad * 4;
        float4 bias = *(const float4*)&b2f_[cog];
        float bb[4] = {bias.x, bias.y, bias.z, bias.w};
#pragma unroll
        for (int tn = 0; tn < 4; ++tn) {
            int sp  = sp_base + wsp + tn * 16 + col;
            int ng  = n0 + (sp >> 10);
            int rem = sp & 1023;
            size_t ob = ((size_t)ng * 512 + cog) * 1024 + rem;
#pragma unroll
            for (int r2 = 0; r2 < 4; ++r2) {
                float v = acc[tm][tn][r2] + bb[r2];
                v = v > 0.f ? v : 0.2f * v;
                v = (v + accs[tm][tn][r2]) * RS2;
                if (flag) ((float*)out)[ob + (size_t)r2 * 1024] = v;
                else      ((u16*)out)[ob + (size_t)r2 * 1024]   = f2b(v);
            }
        }
    }
}

__global__ __launch_bounds__(256, 2) void conv2_kernel(
        const u16* __restrict__ bl1h, const u16* __restrict__ bl1l,
        const u16* __restrict__ skh,  const u16* __restrict__ skl,
        const u16* __restrict__ w2h, const u16* __restrict__ w2l,
        const u16* __restrict__ wsh, const u16* __restrict__ wsl,
        const float* __restrict__ b2f_, const int* __restrict__ flagp,
        void* __restrict__ out, int n0) {
    __shared__ u16 Ah[64 * LDK];
    __shared__ u16 Al[64 * LDK];
    __shared__ u16 Bh[128 * LDK];
    __shared__ u16 Bl[128 * LDK];
    int flag = flagp[0];
    if (flag) conv2_body<true >(bl1h, bl1l, skh, skl, w2h, w2l, wsh, wsl, b2f_, out, n0, Ah, Al, Bh, Bl, flag);
    else      conv2_body<false>(bl1h, bl1l, skh, skl, w2h, w2l, wsh, wsl, b2f_, out, n0, Ah, Al, Bh, Bl, flag);
}

// ---------------------------------------------------------------------------
// Workspace (bytes), total 84,160,512 (same proven footprint):
//   0        flag | 64 inv_sigma
//   1024     b1f  | 2048 b2f
//   4096     w1h  | 1183744 w1l | 2363392 w2h | 4722688 w2l | 7081984 wsh | 7344128 wsl
//   7606272  xt hi/lo planes (16,777,216 each) — aliased after conv1 by blur1
//            hi/lo planes (17,305,600 each); sigma scratch aliased at head
//   42217472 act1 hi/lo bf16 planes (16,777,216 each)
//   75771904 skipin hi/lo planes (4,194,304 each)
// ---------------------------------------------------------------------------
extern "C" void kernel_launch(void* const* d_in, const int* in_sizes, int n_in,
                              void* d_out, int out_size, void* d_ws, size_t ws_size,
                              hipStream_t stream) {
    const void* x   = d_in[0];
    const void* w1b = d_in[1];
    const void* u1  = d_in[2];
    const void* b1  = d_in[4];
    const void* w2b = d_in[5];
    const void* u2  = d_in[6];
    const void* b2  = d_in[8];
    const void* wsb = d_in[9];
    const void* us  = d_in[10];

    char* ws = (char*)d_ws;
    int*   flag      = (int*)(ws);
    float* inv_sigma = (float*)(ws + 64);
    float* b1f       = (float*)(ws + 1024);
    float* b2fp      = (float*)(ws + 2048);
    u16* w1h = (u16*)(ws + 4096);
    u16* w1l = (u16*)(ws + 1183744);
    u16* w2h = (u16*)(ws + 2363392);
    u16* w2l = (u16*)(ws + 4722688);
    u16* wsh = (u16*)(ws + 7081984);
    u16* wsl = (u16*)(ws + 7344128);
    u16* xth  = (u16*)(ws + 7606272);
    u16* xtl  = (u16*)(ws + 7606272 + 16777216);
    u16* bl1h = (u16*)(ws + 7606272);                 // aliased: xt dead after conv1
    u16* bl1l = (u16*)(ws + 7606272 + 17305600);
    u16* a1h = (u16*)(ws + 42217472);
    u16* a1l = (u16*)(ws + 42217472 + 16777216);
    u16* skh = (u16*)(ws + 75771904);
    u16* skl = (u16*)(ws + 75771904 + 4194304);
    // sigma scratch aliased into the head of the xt region (dead before transpose)
    float* tvec  = (float*)(ws + 7606272);            // 4864 floats
    float* ntinv = (float*)(ws + 7606272 + 19456);
    float* ns    = (float*)(ws + 7606272 + 19520);

    detect_kernel<<<1, 256, 0, stream>>>((const unsigned*)x, flag);
    sig_init_kernel<<<19, 256, 0, stream>>>(tvec, ns);
    sig_t_kernel<<<116, 256, 0, stream>>>(w1b, u1, w2b, u2, wsb, us, flag, tvec);
    sig_norm_kernel<<<3, 256, 0, stream>>>(tvec, ntinv);
    sig_s_kernel<<<320, 256, 0, stream>>>(w1b, w2b, wsb, flag, tvec, ntinv, ns);
    sig_fin_kernel<<<1, 64, 0, stream>>>(ns, inv_sigma);
    wprep_kernel<<<7427, 256, 0, stream>>>(w1b, w2b, wsb, b1, b2, inv_sigma, flag,
                                           w1h, w1l, w2h, w2l, wsh, wsl, b1f, b2fp);
    for (int c = 0; c < 2; ++c) {
        int n0 = c * 8;
        transpose_kernel<<<dim3(512, 8), 256, 0, stream>>>(x, xth, xtl, flag, n0);
        blursample_kernel<<<1024, 256, 0, stream>>>(xth, xtl, skh, skl);
        conv1_kernel<<<dim3(256, 2), 256, 0, stream>>>(xth, xtl, w1h, w1l, b1f, a1h, a1l, flag);
        blur1_kernel<<<1105, 256, 0, stream>>>(a1h, a1l, bl1h, bl1l);
        conv2_kernel<<<512, 256, 0, stream>>>(bl1h, bl1l, skh, skl, w2h, w2l,
                                              wsh, wsl, b2fp, flag, d_out, n0);
    }
}